// Round 3
// baseline (847.050 us; speedup 1.0000x reference)
//
#include <hip/hip_runtime.h>

typedef __attribute__((ext_vector_type(8))) short bf16x8;
typedef __attribute__((ext_vector_type(4))) float f32x4;

#define DEVINL __device__ __forceinline__
#define AS1 __attribute__((address_space(1)))
#define AS3 __attribute__((address_space(3)))

constexpr int BB = 4, SS = 4096, DD = 1024, LL = 8192;
constexpr int NS = 2, SCHUNK = SS / NS;      // 2048 s per block
constexpr int LTILE = 256, STILE = 128, BK = 64;
constexpr int NST = SCHUNK / STILE;          // 16 s-tiles
constexpr int KST = DD / BK;                 // 16 k-steps per phase
constexpr int NU  = NST * 2 * KST;           // 512 pipeline units
constexpr int A_SH = LTILE * BK;             // 16384 shorts (32 KiB)
constexpr int B_SH = STILE * BK;             // 8192 shorts (16 KiB)
constexpr int SLOT_SH = A_SH + B_SH;         // 24576 shorts (48 KiB)

DEVINL unsigned short f2bf(float f){
  union { float f; unsigned u; } a; a.f = f;
  unsigned r = a.u + 0x7fffu + ((a.u >> 16) & 1u);   // RNE
  return (unsigned short)(r >> 16);
}

DEVINL void gll16(const void* src, void* dst){
  __builtin_amdgcn_global_load_lds((const AS1 unsigned int*)src,
                                   (AS3 unsigned int*)dst, 16, 0, 0);
}

// read one MFMA operand fragment: 8 contiguous bf16 at (row, 8-elem chunk),
// xor-8 swizzle matching the pre-swizzled global source in staging.
DEVINL bf16x8 read_frag(const unsigned short* tile, int row, int chunk){
  return *(const AS3 bf16x8*)(tile + row*BK + ((chunk ^ (row & 7)) << 3));
}

__global__ void conv_kernel(const float4* __restrict__ in,
                            ushort4* __restrict__ out, int n4){
  int stride = gridDim.x * blockDim.x;
  for (int i = blockIdx.x*blockDim.x + threadIdx.x; i < n4; i += stride){
    float4 v = in[i];
    ushort4 o;
    o.x = f2bf(v.x); o.y = f2bf(v.y); o.z = f2bf(v.z); o.w = f2bf(v.w);
    out[i] = o;
  }
}

// ---------------- zgemm (round-1 structure, 128x128 tile, 256 thr) --------
constexpr int ZTILE = 128 * BK;   // 8192 shorts per staged tile

DEVINL void stage_tile128(const unsigned short* __restrict__ g0, int row0, int d0,
                          unsigned short* ldsbase, int wave, int lane){
#pragma unroll
  for (int it = 0; it < 4; ++it){
    int off  = it*4096 + wave*1024 + lane*16;   // byte offset inside tile
    int row  = off >> 7;                        // 128 B per row
    int slot = (off >> 4) & 7;
    int scol = (slot ^ (row & 7)) << 3;
    gll16(g0 + (size_t)(row0 + row) * DD + d0 + scol,
          ldsbase + ((it*4096 + wave*1024) >> 1));
  }
}

__global__ __launch_bounds__(256, 2) void zgemm_kernel(
    const unsigned short* __restrict__ X, const unsigned short* __restrict__ W,
    const float* __restrict__ Wb, unsigned short* __restrict__ Z)
{
  __shared__ __align__(16) unsigned short lds[2*ZTILE];   // 32 KiB
  const int bid = blockIdx.x;
  const int tm = bid & 127;
  const int tn = bid >> 7;
  const int tid = threadIdx.x, wave = tid >> 6, lane = tid & 63;
  const int wl = wave >> 1, wn = wave & 1;
  const int g = lane >> 4, cc = lane & 15;

  f32x4 acc[4][4] = {};
#pragma unroll 1
  for (int ks = 0; ks < KST; ++ks){
    __syncthreads();
    stage_tile128(X, tm*128, ks*BK, lds,         wave, lane);
    stage_tile128(W, tn*128, ks*BK, lds + ZTILE, wave, lane);
    __syncthreads();
#pragma unroll
    for (int ksub = 0; ksub < 2; ++ksub){
      bf16x8 af[4], bfr[4];
#pragma unroll
      for (int f = 0; f < 4; ++f) af[f]  = read_frag(lds,         wl*64 + f*16 + cc, ksub*4 + g);
#pragma unroll
      for (int f = 0; f < 4; ++f) bfr[f] = read_frag(lds + ZTILE, wn*64 + f*16 + cc, ksub*4 + g);
#pragma unroll
      for (int fm = 0; fm < 4; ++fm)
#pragma unroll
        for (int fn = 0; fn < 4; ++fn)
          acc[fm][fn] = __builtin_amdgcn_mfma_f32_16x16x32_bf16(af[fm], bfr[fn], acc[fm][fn], 0, 0, 0);
    }
  }
#pragma unroll
  for (int fm = 0; fm < 4; ++fm)
#pragma unroll
    for (int fn = 0; fn < 4; ++fn)
#pragma unroll
      for (int r = 0; r < 4; ++r){
        int row = tm*128 + wl*64 + fm*16 + 4*g + r;
        int col = tn*128 + wn*64 + fn*16 + cc;
        float y = acc[fm][fn][r] + Wb[col];
        float e2 = __expf(2.f * y);
        float t = 1.f - 2.f / (e2 + 1.f);
        Z[(size_t)row*DD + col] = f2bf(t);
      }
}

// ---------------- fused: pipelined dual-GEMM + exp-weighted reduce --------
// Per block: (b, sp, lt) -> 256 L rows x 2048 S. Flat pipeline of NU=512
// units; unit u = (s-tile u>>5, phase (u>>4)&1, k u&15). Phase 0 stages
// (F, X) -> gacc; phase 1 stages (U, Z) -> sacc. 3 LDS slots, prefetch
// depth 2, steady-state s_waitcnt vmcnt(6) (never drained in-loop).
DEVINL void stage_unit(int u, int slot,
                       const unsigned short* Ub, const unsigned short* Fb,
                       const unsigned short* Zb, const unsigned short* Xb,
                       unsigned short* lds, int tid,
                       const int* aoff, const int* boff)
{
  const int st = u >> 5, ph = (u >> 4) & 1, k64 = (u & 15) * 64;
  const unsigned short* As = ph ? Ub : Fb;
  const unsigned short* Bs = (ph ? Zb : Xb) + (size_t)st * (STILE * DD);
  unsigned short* sl = lds + slot * SLOT_SH;
#pragma unroll
  for (int it = 0; it < 4; ++it)
    gll16(As + aoff[it] + k64, sl + (it*512 + tid)*8);
#pragma unroll
  for (int it = 0; it < 2; ++it)
    gll16(Bs + boff[it] + k64, sl + A_SH + (it*512 + tid)*8);
}

// launch_bounds(512, 1): LDS (144 KiB) caps at 1 block/CU anyway; asking the
// allocator for 2 waves/EU (256-reg cap) caused ~107 MB/dispatch of scratch
// spill (round-2 WRITE_SIZE). 1 wave/EU releases the full 512-reg budget.
__global__ __launch_bounds__(512, 1) void fused_kernel(
    const unsigned short* __restrict__ U, const unsigned short* __restrict__ F,
    const unsigned short* __restrict__ Z, const unsigned short* __restrict__ X,
    float* __restrict__ pse, float* __restrict__ pac)
{
  __shared__ __align__(16) unsigned short lds[3 * SLOT_SH];   // 144 KiB

  const int h = blockIdx.x;            // 256 blocks, 1 per CU
  // XCD grouping: xcd = h&7 owns one (b,sp); 32 lt-blocks per XCD share its
  // Z/X chunk (L2/L3-hot); U/F l-tiles stream from L3.
  const int lt = h >> 3, grp = h & 7;
  const int b = grp >> 1, sp = grp & 1;

  const int tid = threadIdx.x;
  const int wave = tid >> 6, lane = tid & 63;
  const int wl = wave >> 1, ws = wave & 1;     // 4 L-waves x 2 S-waves
  const int g = lane >> 4, cc = lane & 15;

  const unsigned short* Ub = U + (size_t)lt * LTILE * DD;
  const unsigned short* Fb = F + (size_t)lt * LTILE * DD;
  const unsigned short* Zb = Z + ((size_t)b * SS + (size_t)sp * SCHUNK) * DD;
  const unsigned short* Xb = X + ((size_t)b * SS + (size_t)sp * SCHUNK) * DD;

  // per-thread staging offsets (pre-swizzled global source, linear LDS dest)
  int aoff[4], boff[2];
#pragma unroll
  for (int it = 0; it < 4; ++it){
    int c = it*512 + tid, row = c >> 3, s0 = c & 7;
    aoff[it] = row*DD + ((s0 ^ (row & 7)) << 3);
  }
#pragma unroll
  for (int it = 0; it < 2; ++it){
    int c = it*512 + tid, row = c >> 3, s0 = c & 7;
    boff[it] = row*DD + ((s0 ^ (row & 7)) << 3);
  }

  f32x4 sacc[4][4] = {}, gacc[4][4] = {};
  float se_st[4][4] = {}, ac_st[4][4] = {};

  stage_unit(0, 0, Ub, Fb, Zb, Xb, lds, tid, aoff, boff);
  stage_unit(1, 1, Ub, Fb, Zb, Xb, lds, tid, aoff, boff);

#pragma unroll 1
  for (int u = 0; u < NU; ++u){
    // own unit-u loads complete (6 newer stay in flight), then block-sync.
    asm volatile("s_waitcnt vmcnt(6)" ::: "memory");
    __builtin_amdgcn_s_barrier();

    // prefetch unit u+2 (wrap at tail keeps vmcnt uniform; wrapped stages
    // are harmless re-loads into a slot nobody reads afterwards).
    int un = u + 2; if (un >= NU) un -= NU;
    stage_unit(un, (u + 2) % 3, Ub, Fb, Zb, Xb, lds, tid, aoff, boff);

    const unsigned short* At = lds + (u % 3) * SLOT_SH;   // [256][64]
    const unsigned short* Bt = At + A_SH;                 // [128][64]
    const int ph = (u >> 4) & 1;

#pragma unroll
    for (int ksub = 0; ksub < 2; ++ksub){
      bf16x8 a0[4], b0[4];
#pragma unroll
      for (int f = 0; f < 4; ++f) a0[f] = read_frag(At, wl*64 + f*16 + cc, ksub*4 + g);
#pragma unroll
      for (int f = 0; f < 4; ++f) b0[f] = read_frag(Bt, ws*64 + f*16 + cc, ksub*4 + g);
      __builtin_amdgcn_s_setprio(1);
      if (ph == 0){
#pragma unroll
        for (int fm = 0; fm < 4; ++fm)
#pragma unroll
          for (int fn = 0; fn < 4; ++fn)
            gacc[fm][fn] = __builtin_amdgcn_mfma_f32_16x16x32_bf16(a0[fm], b0[fn], gacc[fm][fn], 0, 0, 0);
      } else {
#pragma unroll
        for (int fm = 0; fm < 4; ++fm)
#pragma unroll
          for (int fn = 0; fn < 4; ++fn)
            sacc[fm][fn] = __builtin_amdgcn_mfma_f32_16x16x32_bf16(a0[fm], b0[fn], sacc[fm][fn], 0, 0, 0);
      }
      __builtin_amdgcn_s_setprio(0);
    }

    // end of s-tile: exp-weight scores, fold G, reset accumulators.
    if ((u & 31) == 31){
#pragma unroll
      for (int fm = 0; fm < 4; ++fm)
#pragma unroll
        for (int r = 0; r < 4; ++r){
          float ps = 0.f, pg = 0.f;
#pragma unroll
          for (int fn = 0; fn < 4; ++fn){
            float p = __expf(sacc[fm][fn][r]);     // |score| << 88, max-free safe
            ps += p;
            pg += p * gacc[fm][fn][r];
          }
          se_st[fm][r] += ps;
          ac_st[fm][r] += pg;
        }
#pragma unroll
      for (int fm = 0; fm < 4; ++fm)
#pragma unroll
        for (int fn = 0; fn < 4; ++fn){
          sacc[fm][fn] = f32x4{0.f, 0.f, 0.f, 0.f};
          gacc[fm][fn] = f32x4{0.f, 0.f, 0.f, 0.f};
        }
    }
  }

  // reduce across the 16 s-columns per lane group, write per-(sp,ws) partials
#pragma unroll
  for (int fm = 0; fm < 4; ++fm)
#pragma unroll
    for (int r = 0; r < 4; ++r){
      float s = se_st[fm][r], a = ac_st[fm][r];
#pragma unroll
      for (int m = 1; m < 16; m <<= 1){
        s += __shfl_xor(s, m, 64);
        a += __shfl_xor(a, m, 64);
      }
      if (cc == 0){
        int l = lt*LTILE + wl*64 + fm*16 + 4*g + r;
        size_t idx = ((((size_t)b*LL + l)*NS + sp) << 1) + ws;
        pse[idx] = s;
        pac[idx] = a;
      }
    }
}

__global__ void combine_kernel(const float* __restrict__ pse, const float* __restrict__ pac,
                               const float* __restrict__ fb, float* __restrict__ out)
{
  int i = blockIdx.x*blockDim.x + threadIdx.x;
  if (i >= BB*LL) return;
  int l = i & (LL - 1);
  float s = 0.f, a = 0.f;
#pragma unroll
  for (int k = 0; k < NS*2; ++k){
    s += pse[(size_t)i*(NS*2) + k];
    a += pac[(size_t)i*(NS*2) + k];
  }
  out[i] = a / s + fb[l];
}

extern "C" void kernel_launch(void* const* d_in, const int* in_sizes, int n_in,
                              void* d_out, int out_size, void* d_ws, size_t ws_size,
                              hipStream_t stream)
{
  const float* inp = (const float*)d_in[0];   // [B,S,D]
  const float* Ww  = (const float*)d_in[1];   // [D,D]
  const float* Wb  = (const float*)d_in[2];   // [D]
  const float* Uw  = (const float*)d_in[3];   // [L,D]
  const float* Fw  = (const float*)d_in[4];   // [L,D]
  const float* fb  = (const float*)d_in[5];   // [L]
  float* out = (float*)d_out;

  char* ws = (char*)d_ws;
  unsigned short* Xbf = (unsigned short*)(ws);                            // 32 MiB
  unsigned short* Zbf = (unsigned short*)(ws + (size_t)32*1024*1024);     // 32 MiB
  unsigned short* Ubf = (unsigned short*)(ws + (size_t)64*1024*1024);     // 16 MiB
  unsigned short* Fbf = (unsigned short*)(ws + (size_t)80*1024*1024);     // 16 MiB
  unsigned short* Wbf = (unsigned short*)(ws + (size_t)96*1024*1024);     //  2 MiB
  float* pse = (float*)(ws + (size_t)98*1024*1024);                       // 512 KiB
  float* pac = (float*)(ws + (size_t)99*1024*1024);                       // 512 KiB

  conv_kernel<<<2048, 256, 0, stream>>>((const float4*)inp, (ushort4*)Xbf, BB*SS*DD/4);
  conv_kernel<<<256,  256, 0, stream>>>((const float4*)Ww,  (ushort4*)Wbf, DD*DD/4);
  conv_kernel<<<1024, 256, 0, stream>>>((const float4*)Uw,  (ushort4*)Ubf, LL*DD/4);
  conv_kernel<<<1024, 256, 0, stream>>>((const float4*)Fw,  (ushort4*)Fbf, LL*DD/4);

  zgemm_kernel<<<128*8, 256, 0, stream>>>(Xbf, Wbf, Wb, Zbf);
  fused_kernel<<<256, 512, 0, stream>>>(Ubf, Fbf, Zbf, Xbf, pse, pac);
  combine_kernel<<<(BB*LL + 255)/256, 256, 0, stream>>>(pse, pac, fb, out);
}

// Round 4
// 714.041 us; speedup vs baseline: 1.1863x; 1.1863x over previous
//
#include <hip/hip_runtime.h>

typedef __attribute__((ext_vector_type(8))) short bf16x8;
typedef __attribute__((ext_vector_type(4))) float f32x4;

#define DEVINL __device__ __forceinline__
#define AS1 __attribute__((address_space(1)))
#define AS3 __attribute__((address_space(3)))

constexpr int BB = 4, SS = 4096, DD = 1024, LL = 8192;
constexpr int NS = 2, SCHUNK = SS / NS;      // 2048 s per block
constexpr int LTILE = 128, STILE = 128, BK = 64;
constexpr int NST = SCHUNK / STILE;          // 16 s-tiles
constexpr int KST = DD / BK;                 // 16 k-steps per phase
constexpr int NU  = NST * 2 * KST;           // 512 pipeline units
constexpr int A_SH = LTILE * BK;             // 8192 shorts (16 KiB)
constexpr int B_SH = STILE * BK;             // 8192 shorts (16 KiB)
constexpr int SLOT_SH = A_SH + B_SH;         // 16384 shorts (32 KiB)

DEVINL unsigned short f2bf(float f){
  union { float f; unsigned u; } a; a.f = f;
  unsigned r = a.u + 0x7fffu + ((a.u >> 16) & 1u);   // RNE
  return (unsigned short)(r >> 16);
}

DEVINL void gll16(const void* src, void* dst){
  __builtin_amdgcn_global_load_lds((const AS1 unsigned int*)src,
                                   (AS3 unsigned int*)dst, 16, 0, 0);
}

// read one MFMA operand fragment: 8 contiguous bf16 at (row, 8-elem chunk),
// xor-8 swizzle matching the pre-swizzled global source in staging.
DEVINL bf16x8 read_frag(const unsigned short* tile, int row, int chunk){
  return *(const AS3 bf16x8*)(tile + row*BK + ((chunk ^ (row & 7)) << 3));
}

__global__ void conv_kernel(const float4* __restrict__ in,
                            ushort4* __restrict__ out, int n4){
  int stride = gridDim.x * blockDim.x;
  for (int i = blockIdx.x*blockDim.x + threadIdx.x; i < n4; i += stride){
    float4 v = in[i];
    ushort4 o;
    o.x = f2bf(v.x); o.y = f2bf(v.y); o.z = f2bf(v.z); o.w = f2bf(v.w);
    out[i] = o;
  }
}

// ---------------- zgemm (round-1 structure, 128x128 tile, 256 thr) --------
constexpr int ZTILE = 128 * BK;   // 8192 shorts per staged tile

DEVINL void stage_tile128(const unsigned short* __restrict__ g0, int row0, int d0,
                          unsigned short* ldsbase, int wave, int lane){
#pragma unroll
  for (int it = 0; it < 4; ++it){
    int off  = it*4096 + wave*1024 + lane*16;   // byte offset inside tile
    int row  = off >> 7;                        // 128 B per row
    int slot = (off >> 4) & 7;
    int scol = (slot ^ (row & 7)) << 3;
    gll16(g0 + (size_t)(row0 + row) * DD + d0 + scol,
          ldsbase + ((it*4096 + wave*1024) >> 1));
  }
}

__global__ __launch_bounds__(256, 2) void zgemm_kernel(
    const unsigned short* __restrict__ X, const unsigned short* __restrict__ W,
    const float* __restrict__ Wb, unsigned short* __restrict__ Z)
{
  __shared__ __align__(16) unsigned short lds[2*ZTILE];   // 32 KiB
  const int bid = blockIdx.x;
  const int tm = bid & 127;
  const int tn = bid >> 7;
  const int tid = threadIdx.x, wave = tid >> 6, lane = tid & 63;
  const int wl = wave >> 1, wn = wave & 1;
  const int g = lane >> 4, cc = lane & 15;

  f32x4 acc[4][4] = {};
#pragma unroll 1
  for (int ks = 0; ks < KST; ++ks){
    __syncthreads();
    stage_tile128(X, tm*128, ks*BK, lds,         wave, lane);
    stage_tile128(W, tn*128, ks*BK, lds + ZTILE, wave, lane);
    __syncthreads();
#pragma unroll
    for (int ksub = 0; ksub < 2; ++ksub){
      bf16x8 af[4], bfr[4];
#pragma unroll
      for (int f = 0; f < 4; ++f) af[f]  = read_frag(lds,         wl*64 + f*16 + cc, ksub*4 + g);
#pragma unroll
      for (int f = 0; f < 4; ++f) bfr[f] = read_frag(lds + ZTILE, wn*64 + f*16 + cc, ksub*4 + g);
#pragma unroll
      for (int fm = 0; fm < 4; ++fm)
#pragma unroll
        for (int fn = 0; fn < 4; ++fn)
          acc[fm][fn] = __builtin_amdgcn_mfma_f32_16x16x32_bf16(af[fm], bfr[fn], acc[fm][fn], 0, 0, 0);
    }
  }
#pragma unroll
  for (int fm = 0; fm < 4; ++fm)
#pragma unroll
    for (int fn = 0; fn < 4; ++fn)
#pragma unroll
      for (int r = 0; r < 4; ++r){
        int row = tm*128 + wl*64 + fm*16 + 4*g + r;
        int col = tn*128 + wn*64 + fn*16 + cc;
        float y = acc[fm][fn][r] + Wb[col];
        float e2 = __expf(2.f * y);
        float t = 1.f - 2.f / (e2 + 1.f);
        Z[(size_t)row*DD + col] = f2bf(t);
      }
}

// ---------------- fused: pipelined dual-GEMM + exp-weighted reduce --------
// 512 blocks x 256 thr (4 waves), 2 blocks/CU (64 KiB LDS, <=256 regs).
// Per block: (lt, b, sp) -> 128 L x 2048 S. Flat pipeline of NU=512 units;
// unit u = (s-tile u>>5, phase (u>>4)&1, k u&15). Phase 0 stages (F, X[st])
// -> gacc; phase 1 stages (U, Z[st]) -> sacc. 2 LDS slots, depth-1 prefetch,
// steady-state s_waitcnt vmcnt(8), stage wraps at tail (harmless re-loads).
__global__ __launch_bounds__(256, 2) void fused_kernel(
    const unsigned short* __restrict__ U, const unsigned short* __restrict__ F,
    const unsigned short* __restrict__ Z, const unsigned short* __restrict__ X,
    float* __restrict__ pse, float* __restrict__ pac)
{
  __shared__ __align__(16) unsigned short lds[2 * SLOT_SH];   // 64 KiB

  const int h = blockIdx.x;            // 512 blocks, 2 per CU
  // L2 regroup: XCD x owns lt in [x*8, x*8+8) (A working set 4 MB ~ L2) and
  // all 8 (b,sp) chunks; 8 lockstep blocks share each A-tile and each
  // B-chunk through the XCD's L2.
  const int xcd = h & 7, j = h >> 3;   // j in 0..63
  const int lt = xcd * 8 + (j & 7);    // 0..63
  const int chunk = j >> 3;            // 0..7
  const int b = chunk >> 1, sp = chunk & 1;

  const int tid = threadIdx.x;
  const int wave = tid >> 6, lane = tid & 63;
  const int wl = wave >> 1, ws = wave & 1;     // 2 L-waves x 2 S-waves
  const int g = lane >> 4, cc = lane & 15;

  const unsigned short* Ub = U + (size_t)lt * LTILE * DD;
  const unsigned short* Fb = F + (size_t)lt * LTILE * DD;
  const unsigned short* Zb = Z + ((size_t)b * SS + (size_t)sp * SCHUNK) * DD;
  const unsigned short* Xb = X + ((size_t)b * SS + (size_t)sp * SCHUNK) * DD;

  // staging offsets: [128 x 64]-short tile = 1024 16B-chunks; thread handles
  // chunks {tid, tid+256, tid+512, tid+768}. Pre-swizzled global source,
  // linear LDS dest (both A and B tiles have row stride DD in global).
  int aoff[4];
#pragma unroll
  for (int it = 0; it < 4; ++it){
    int c = it*256 + tid, row = c >> 3, s0 = c & 7;
    aoff[it] = row*DD + ((s0 ^ (row & 7)) << 3);
  }

  f32x4 sacc[4][4] = {}, gacc[4][4] = {};
  float se_st[4][4] = {}, ac_st[4][4] = {};

  // ---- stage unit u into slot (8 gll16 per thread) ----
  auto stage_unit = [&](int u, int slot){
    const int st = u >> 5, ph = (u >> 4) & 1, k64 = (u & 15) * 64;
    const unsigned short* As = ph ? Ub : Fb;
    const unsigned short* Bs = (ph ? Zb : Xb) + (size_t)st * (STILE * DD);
    unsigned short* sl = lds + slot * SLOT_SH;
#pragma unroll
    for (int it = 0; it < 4; ++it)
      gll16(As + aoff[it] + k64, sl + (it*256 + tid)*8);
#pragma unroll
    for (int it = 0; it < 4; ++it)
      gll16(Bs + aoff[it] + k64, sl + A_SH + (it*256 + tid)*8);
  };

  stage_unit(0, 0);
  stage_unit(1, 1);

#pragma unroll 1
  for (int u = 0; u < NU; ++u){
    // own unit-u loads complete (8 of unit u+1 stay in flight), block-sync.
    asm volatile("s_waitcnt vmcnt(8)" ::: "memory");
    __builtin_amdgcn_s_barrier();

    const unsigned short* At = lds + (u & 1) * SLOT_SH;   // [128][64]
    const unsigned short* Bt = At + A_SH;                 // [128][64]
    const int ph = (u >> 4) & 1;

#pragma unroll
    for (int ksub = 0; ksub < 2; ++ksub){
      bf16x8 a0[4], b0[4];
#pragma unroll
      for (int f = 0; f < 4; ++f) a0[f] = read_frag(At, wl*64 + f*16 + cc, ksub*4 + g);
#pragma unroll
      for (int f = 0; f < 4; ++f) b0[f] = read_frag(Bt, ws*64 + f*16 + cc, ksub*4 + g);
      __builtin_amdgcn_s_setprio(1);
      if (ph == 0){
#pragma unroll
        for (int fm = 0; fm < 4; ++fm)
#pragma unroll
          for (int fn = 0; fn < 4; ++fn)
            gacc[fm][fn] = __builtin_amdgcn_mfma_f32_16x16x32_bf16(a0[fm], b0[fn], gacc[fm][fn], 0, 0, 0);
      } else {
#pragma unroll
        for (int fm = 0; fm < 4; ++fm)
#pragma unroll
          for (int fn = 0; fn < 4; ++fn)
            sacc[fm][fn] = __builtin_amdgcn_mfma_f32_16x16x32_bf16(a0[fm], b0[fn], sacc[fm][fn], 0, 0, 0);
      }
      __builtin_amdgcn_s_setprio(0);
    }

    // all waves done reading slot u&1 -> safe to overwrite with unit u+2.
    __builtin_amdgcn_s_barrier();
    int un = u + 2; if (un >= NU) un -= NU;   // tail wrap keeps vmcnt uniform
    stage_unit(un, u & 1);

    // end of s-tile (after ph=1 k-loop): exp-weight scores, fold G, reset.
    if ((u & 31) == 31){
#pragma unroll
      for (int fm = 0; fm < 4; ++fm)
#pragma unroll
        for (int r = 0; r < 4; ++r){
          float ps = 0.f, pg = 0.f;
#pragma unroll
          for (int fn = 0; fn < 4; ++fn){
            float p = __expf(sacc[fm][fn][r]);     // |score| << 88, max-free safe
            ps += p;
            pg += p * gacc[fm][fn][r];
          }
          se_st[fm][r] += ps;
          ac_st[fm][r] += pg;
        }
#pragma unroll
      for (int fm = 0; fm < 4; ++fm)
#pragma unroll
        for (int fn = 0; fn < 4; ++fn){
          sacc[fm][fn] = f32x4{0.f, 0.f, 0.f, 0.f};
          gacc[fm][fn] = f32x4{0.f, 0.f, 0.f, 0.f};
        }
    }
  }

  // reduce across the 16 s-columns per lane group, write per-(sp,ws) partials
#pragma unroll
  for (int fm = 0; fm < 4; ++fm)
#pragma unroll
    for (int r = 0; r < 4; ++r){
      float s = se_st[fm][r], a = ac_st[fm][r];
#pragma unroll
      for (int m = 1; m < 16; m <<= 1){
        s += __shfl_xor(s, m, 64);
        a += __shfl_xor(a, m, 64);
      }
      if (cc == 0){
        int l = lt*LTILE + wl*64 + fm*16 + 4*g + r;
        size_t idx = ((((size_t)b*LL + l)*NS + sp) << 1) + ws;
        pse[idx] = s;
        pac[idx] = a;
      }
    }
}

__global__ void combine_kernel(const float* __restrict__ pse, const float* __restrict__ pac,
                               const float* __restrict__ fb, float* __restrict__ out)
{
  int i = blockIdx.x*blockDim.x + threadIdx.x;
  if (i >= BB*LL) return;
  int l = i & (LL - 1);
  float s = 0.f, a = 0.f;
#pragma unroll
  for (int k = 0; k < NS*2; ++k){
    s += pse[(size_t)i*(NS*2) + k];
    a += pac[(size_t)i*(NS*2) + k];
  }
  out[i] = a / s + fb[l];
}

extern "C" void kernel_launch(void* const* d_in, const int* in_sizes, int n_in,
                              void* d_out, int out_size, void* d_ws, size_t ws_size,
                              hipStream_t stream)
{
  const float* inp = (const float*)d_in[0];   // [B,S,D]
  const float* Ww  = (const float*)d_in[1];   // [D,D]
  const float* Wb  = (const float*)d_in[2];   // [D]
  const float* Uw  = (const float*)d_in[3];   // [L,D]
  const float* Fw  = (const float*)d_in[4];   // [L,D]
  const float* fb  = (const float*)d_in[5];   // [L]
  float* out = (float*)d_out;

  char* ws = (char*)d_ws;
  unsigned short* Xbf = (unsigned short*)(ws);                            // 32 MiB
  unsigned short* Zbf = (unsigned short*)(ws + (size_t)32*1024*1024);     // 32 MiB
  unsigned short* Ubf = (unsigned short*)(ws + (size_t)64*1024*1024);     // 16 MiB
  unsigned short* Fbf = (unsigned short*)(ws + (size_t)80*1024*1024);     // 16 MiB
  unsigned short* Wbf = (unsigned short*)(ws + (size_t)96*1024*1024);     //  2 MiB
  float* pse = (float*)(ws + (size_t)98*1024*1024);                       // 512 KiB
  float* pac = (float*)(ws + (size_t)99*1024*1024);                       // 512 KiB

  conv_kernel<<<2048, 256, 0, stream>>>((const float4*)inp, (ushort4*)Xbf, BB*SS*DD/4);
  conv_kernel<<<256,  256, 0, stream>>>((const float4*)Ww,  (ushort4*)Wbf, DD*DD/4);
  conv_kernel<<<1024, 256, 0, stream>>>((const float4*)Uw,  (ushort4*)Ubf, LL*DD/4);
  conv_kernel<<<1024, 256, 0, stream>>>((const float4*)Fw,  (ushort4*)Fbf, LL*DD/4);

  zgemm_kernel<<<128*8, 256, 0, stream>>>(Xbf, Wbf, Wb, Zbf);
  fused_kernel<<<512, 256, 0, stream>>>(Ubf, Fbf, Zbf, Xbf, pse, pac);
  combine_kernel<<<(BB*LL + 255)/256, 256, 0, stream>>>(pse, pac, fb, out);
}